// Round 8
// baseline (511.127 us; speedup 1.0000x reference)
//
#include <hip/hip_runtime.h>

#define N_NODES 100000
#define N_EDGES 1600000
#define IN_DIM 500
#define HID 32
#define N_REL 7
#define OUT_DIM 4
#define N_GRAPHS 16
#define NC 256      // (N_REL + 1) * HID: [root | rel0..rel6]
#define MC 224      // message cols (N_REL * HID)
#define KPAD 512

// dst-bucketing: 64 nodes/bucket; 8 sub-cursors/bucket (indexed by XCD slot)
#define BK_SHIFT 6
#define BK_NODES 64
#define N_BUCKETS ((N_NODES + BK_NODES - 1) / BK_NODES)   // 1563
#define NSUB 8
#define SUB_CAP 256
#define BK_CAP (NSUB * SUB_CAP)  // 2048
#define NPOOL 8

// merged gemm+bin grid: groups of 8 consecutive blocks (one per XCD);
// gemm tiles M=32 -> 3125 blocks; bin 6250 blocks; every 3rd group is gemm.
#define GEMM_BLOCKS 3125                         // 3125*32 == N_NODES exactly
#define BIN_BLOCKS  ((N_EDGES + 255) / 256)      // 6250
#define N_GROUPS 1173                            // 391 gemm + 782 bin groups
#define GRID_MERGED (N_GROUPS * 8)               // 9384

typedef __attribute__((ext_vector_type(8))) short bf16x8;
typedef __attribute__((ext_vector_type(4))) float f32x4;

__device__ inline unsigned short f2bf(float f) {
    unsigned u = __float_as_uint(f);
    unsigned r = (u + 0x7FFFu + ((u >> 16) & 1u)) >> 16;
    return (unsigned short)r;
}
__device__ inline float bf2f(unsigned short b) {
    return __uint_as_float((unsigned)b << 16);
}

// pack 8 f32 (two float4, k-ascending) into one bf16x8 fragment
__device__ inline bf16x8 pack8(float4 lo, float4 hi) {
    union { unsigned u[4]; bf16x8 v; } r;
    r.u[0] = ((unsigned)f2bf(lo.y) << 16) | f2bf(lo.x);
    r.u[1] = ((unsigned)f2bf(lo.w) << 16) | f2bf(lo.z);
    r.u[2] = ((unsigned)f2bf(hi.y) << 16) | f2bf(hi.x);
    r.u[3] = ((unsigned)f2bf(hi.w) << 16) | f2bf(hi.z);
    return r.v;
}

// ---------------- build Wbf + init bcur + zero pooled (fused tiny setup) ---
__global__ void build_wbf(const float* __restrict__ W_root,
                          const float* __restrict__ W_rel,
                          unsigned short* __restrict__ Wbf,
                          int* __restrict__ bcur,
                          float* __restrict__ pooled) {
    int idx = blockIdx.x * blockDim.x + threadIdx.x;   // 0 .. KPAD*NC-1
    if (idx < N_BUCKETS * NSUB) bcur[idx] = idx * SUB_CAP;
    if (idx < NPOOL * N_GRAPHS * HID) pooled[idx] = 0.f;
    if (idx >= KPAD * NC) return;
    int kk = idx >> 8;
    int n = idx & 255;
    float v = 0.f;
    if (kk < IN_DIM) {
        if (n < HID) v = W_root[kk * HID + n];
        else {
            int r = (n >> 5) - 1;
            v = W_rel[((size_t)r * IN_DIM + kk) * HID + (n & 31)];
        }
    }
    int ks = kk >> 5, q = (kk >> 3) & 3, j = kk & 7;
    Wbf[(size_t)((((ks << 2) + q) << 8) + n) * 8 + j] = f2bf(v);
}

// ---------------- merged: barrier-free MFMA GEMM (M=32) + bin_edges --------
// gemm: NO LDS, NO barriers. Each lane loads its A-fragment (8 contiguous
// f32 of one row) directly from global, packs to bf16 in-register. The
// compiler software-pipelines the 16 unrolled k-steps freely (the LDS
// version's __syncthreads forced a vmcnt(0) drain every half -> 6% MfmaUtil).
// K-pad: load offset clamped to 496 (in-row); k>=500 lanes annihilated by
// Wbf's zero rows. bin: scatter edges into (bucket, xcd-slot) sub-regions.
__global__ __launch_bounds__(256, 4) void gemm_bin(const float* __restrict__ A,
                                                   const uint4* __restrict__ Wbf,
                                                   float* __restrict__ Hr,
                                                   unsigned short* __restrict__ Hm,
                                                   const int* __restrict__ src,
                                                   const int* __restrict__ dst,
                                                   const int* __restrict__ attr,
                                                   int* __restrict__ bcur,
                                                   int* __restrict__ rec) {
    const int grp = blockIdx.x >> 3, j8 = blockIdx.x & 7;

    if (grp % 3 != 0) {
        // ---------------- bin_edges role ----------------
        int bb = (grp - grp / 3 - 1) * 8 + j8;
        if (bb >= BIN_BLOCKS) return;
        int e = bb * 256 + threadIdx.x;
        if (e >= N_EDGES) return;
        int d = dst[e];
        int cur = (d >> BK_SHIFT) * NSUB + j8;   // j8 == XCD slot
        int p = atomicAdd(&bcur[cur], 1);
        if (p < (cur + 1) * SUB_CAP)   // overflow guard (prob ~ 0)
            rec[p] = ((d & (BK_NODES - 1)) << 20) | (src[e] << 3) | attr[e];
        return;
    }

    // ---------------- gemm role ----------------
    int bid = (grp / 3) * 8 + j8;
    if (bid >= GEMM_BLOCKS) return;

    const int tid = threadIdx.x;
    const int wave = tid >> 6, lane = tid & 63;
    const int l16 = lane & 15, q = lane >> 4;
    const int row0 = bid * 32;
    const int wn = wave * 64;

    const float* Ar0 = A + (size_t)(row0 + l16) * IN_DIM;
    const float* Ar1 = Ar0 + 16 * IN_DIM;
    const int kb = q * 8;                     // lane's k offset within k-step

    f32x4 acc[2][4];
    #pragma unroll
    for (int mt = 0; mt < 2; mt++)
        #pragma unroll
        for (int nt = 0; nt < 4; nt++)
            #pragma unroll
            for (int r = 0; r < 4; r++) acc[mt][nt][r] = 0.f;

    #pragma unroll
    for (int ksq = 0; ksq < 16; ksq++) {
        int kbase = ksq * 32 + kb;
        int o0 = kbase <= 496 ? kbase : 496;         // clamp: stay in-row
        int o1 = kbase + 4 <= 496 ? kbase + 4 : 496; // garbage x 0-Wbf = 0
        float4 a00 = *(const float4*)(Ar0 + o0);
        float4 a01 = *(const float4*)(Ar0 + o1);
        float4 a10 = *(const float4*)(Ar1 + o0);
        float4 a11 = *(const float4*)(Ar1 + o1);
        bf16x8 bfr[4];
        #pragma unroll
        for (int nt = 0; nt < 4; nt++) {
            uint4 t = Wbf[(size_t)((((ksq << 2) | q)) << 8) + wn + nt * 16 + l16];
            bfr[nt] = *(bf16x8*)&t;
        }
        bf16x8 afr0 = pack8(a00, a01);
        bf16x8 afr1 = pack8(a10, a11);
        #pragma unroll
        for (int nt = 0; nt < 4; nt++)
            acc[0][nt] = __builtin_amdgcn_mfma_f32_16x16x32_bf16(
                afr0, bfr[nt], acc[0][nt], 0, 0, 0);
        #pragma unroll
        for (int nt = 0; nt < 4; nt++)
            acc[1][nt] = __builtin_amdgcn_mfma_f32_16x16x32_bf16(
                afr1, bfr[nt], acc[1][nt], 0, 0, 0);
    }

    // ---- store: C/D layout col=lane&15, row=(lane>>4)*4+reg ----
    #pragma unroll
    for (int mt = 0; mt < 2; mt++) {
        int rbase = row0 + mt * 16 + q * 4;
        #pragma unroll
        for (int r = 0; r < 4; r++) {
            int row = rbase + r;
            #pragma unroll
            for (int nt = 0; nt < 4; nt++) {
                int col = wn + nt * 16 + l16;
                float v = acc[mt][nt][r];
                if (wave == 0 && nt < 2)            // col < 32: root slice
                    Hr[(size_t)row * HID + col] = v;
                else
                    Hm[(size_t)row * MC + (col - HID)] = f2bf(v);
            }
        }
    }
}

// ---------------- per-bucket LDS counting sort + deg/offs/invcnt -----------
__global__ __launch_bounds__(256) void bucket_sort(int* __restrict__ rec,
                                                   const int* __restrict__ bcur,
                                                   int* __restrict__ deg,
                                                   int* __restrict__ offs,
                                                   float* __restrict__ invcnt) {
    __shared__ int h2[BK_NODES * N_REL];   // per-(node,rel) counts
    __shared__ int lcur[BK_NODES];         // scatter cursors
    __shared__ int sorted[BK_CAP];         // 8 KB
    __shared__ int scnt[NSUB];
    __shared__ int s_total;

    const int b = blockIdx.x, t = threadIdx.x;
    const int n0 = b << BK_SHIFT;
    const size_t rbase = (size_t)b * BK_CAP;

    for (int i = t; i < BK_NODES * N_REL; i += 256) h2[i] = 0;
    if (t < NSUB) {
        int c = bcur[b * NSUB + t] - (b * NSUB + t) * SUB_CAP;
        scnt[t] = c < SUB_CAP ? c : SUB_CAP;
    }
    __syncthreads();

    for (int s = 0; s < NSUB; s++) {
        int cs = scnt[s];
        const int* rp = rec + rbase + s * SUB_CAP;
        for (int i = t; i < cs; i += 256) {
            int q = rp[i];
            atomicAdd(&h2[(q >> 20) * N_REL + (q & 7)], 1);
        }
    }
    __syncthreads();

    if (t < BK_NODES) {       // wave 0: per-node totals + exclusive scan
        int tot = 0;
        #pragma unroll
        for (int r = 0; r < N_REL; r++) tot += h2[t * N_REL + r];
        int incl = tot;
        #pragma unroll
        for (int off = 1; off < BK_NODES; off <<= 1) {
            int y = __shfl_up(incl, off, 64);
            if (t >= off) incl += y;
        }
        int excl = incl - tot;
        lcur[t] = excl;
        if (t == BK_NODES - 1) s_total = incl;
        int n = n0 + t;
        if (n < N_NODES) {
            deg[n] = tot;
            offs[n] = (int)rbase + excl;
        }
    }
    int lim = (N_NODES - n0) * N_REL;
    if (lim > BK_NODES * N_REL) lim = BK_NODES * N_REL;
    for (int i = t; i < lim; i += 256) {
        int cc = h2[i];
        invcnt[(size_t)n0 * N_REL + i] = 1.0f / (float)(cc > 1 ? cc : 1);
    }
    __syncthreads();

    for (int s = 0; s < NSUB; s++) {
        int cs = scnt[s];
        const int* rp = rec + rbase + s * SUB_CAP;
        for (int i = t; i < cs; i += 256) {
            int q = rp[i];
            int p = atomicAdd(&lcur[q >> 20], 1);
            if (p < BK_CAP)                       // defensive
                sorted[p] = q & 0xFFFFF;          // strip ldst: (src<<3)|rel
        }
    }
    __syncthreads();

    int total = s_total;
    if (total > BK_CAP) total = BK_CAP;           // defensive
    for (int i = t; i < total; i += 256) rec[rbase + i] = sorted[i];
}

// ---------------- gather aggregation: one HALF-wave (32 lanes) per node ----
// fully predicated 8-deep loop; fused relu+bias+graph pooling.
__global__ __launch_bounds__(256) void gather_agg(const int* __restrict__ rec,
                                                  const int* __restrict__ offs,
                                                  const int* __restrict__ deg,
                                                  const float* __restrict__ invcnt,
                                                  const float* __restrict__ bias,
                                                  const unsigned short* __restrict__ Hm,
                                                  const float* __restrict__ Hr,
                                                  const int* __restrict__ batch,
                                                  float* __restrict__ pooled) {
    __shared__ float lpool[N_GRAPHS][HID];
    const int t = threadIdx.x;
    for (int i = t; i < N_GRAPHS * HID; i += 256) ((float*)lpool)[i] = 0.f;
    __syncthreads();

    const int d = blockIdx.x * 8 + (t >> 5);   // 12500*8 == N_NODES exactly
    const int c = t & 31;

    int dg = deg[d];
    int start = offs[d];
    int end = start + dg;

    float acc = 0.f;
    // predicated 8-deep: rec reads beyond end stay inside ws (bucket slack);
    // masked records forced to q=0, weight=0.
    for (int i = start; i < end; i += 8) {
        int q[8];
        float h[8], w[8];
        #pragma unroll
        for (int j = 0; j < 8; j++) {
            bool ok = (i + j) < end;
            int qq = rec[i + j];
            q[j] = ok ? qq : 0;
            w[j] = ok ? 1.f : 0.f;
        }
        #pragma unroll
        for (int j = 0; j < 8; j++)
            h[j] = bf2f(Hm[(size_t)((q[j] >> 3) & 0x1FFFF) * MC + (q[j] & 7) * HID + c]);
        #pragma unroll
        for (int j = 0; j < 8; j++)
            acc = fmaf(h[j], w[j] * invcnt[d * N_REL + (q[j] & 7)], acc);
    }

    float v = Hr[(size_t)d * HID + c] + bias[c] + acc;
    v = fmaxf(v, 0.f);
    atomicAdd(&lpool[batch[d]][c], v);
    __syncthreads();

    float* pp = pooled + (size_t)(blockIdx.x & (NPOOL - 1)) * N_GRAPHS * HID;
    for (int i2 = t; i2 < N_GRAPHS * HID; i2 += 256) {
        float v2 = ((float*)lpool)[i2];
        if (v2 != 0.f) atomicAdd(&pp[i2], v2);
    }
}

// ---------------- final FC (sums the NPOOL partial slices) ----------
__global__ void fc_kernel(const float* __restrict__ pooled, const float* __restrict__ fc_w,
                          const float* __restrict__ fc_b, float* __restrict__ out) {
    int t = threadIdx.x;
    if (t >= N_GRAPHS * OUT_DIM) return;
    int g = t >> 2, o = t & 3;
    float acc = fc_b[o];
    #pragma unroll
    for (int c = 0; c < HID; c++) {
        float p = 0.f;
        #pragma unroll
        for (int k = 0; k < NPOOL; k++)
            p += pooled[(size_t)(k * N_GRAPHS + g) * HID + c];
        acc += p * fc_w[c * OUT_DIM + o];
    }
    out[t] = acc;
}

extern "C" void kernel_launch(void* const* d_in, const int* in_sizes, int n_in,
                              void* d_out, int out_size, void* d_ws, size_t ws_size,
                              hipStream_t stream) {
    const float* node_x  = (const float*)d_in[0];
    const int*   edge_ix = (const int*)d_in[1];
    const int*   e_attr  = (const int*)d_in[2];
    const int*   batch   = (const int*)d_in[3];
    const float* W_rel   = (const float*)d_in[4];
    const float* W_root  = (const float*)d_in[5];
    const float* bias    = (const float*)d_in[6];
    const float* fc_w    = (const float*)d_in[7];
    const float* fc_b    = (const float*)d_in[8];
    float* out = (float*)d_out;

    char* ws = (char*)d_ws;
    size_t off = 0;
    auto alloc = [&](size_t bytes) {
        char* p = ws + off;
        off += (bytes + 255) & ~(size_t)255;
        return p;
    };
    unsigned short* Wbf = (unsigned short*)alloc((size_t)KPAD * NC * 2);   // 256 KB
    float* Hr      = (float*)alloc((size_t)N_NODES * HID * 4);             // 12.8 MB
    unsigned short* Hm = (unsigned short*)alloc((size_t)N_NODES * MC * 2); // 44.8 MB
    int*   rec     = (int*)  alloc((size_t)N_BUCKETS * BK_CAP * 4);        // 12.8 MB
    int*   bcur    = (int*)  alloc((size_t)N_BUCKETS * NSUB * 4);          // 50 KB
    int*   deg     = (int*)  alloc((size_t)N_NODES * 4);
    int*   offsb   = (int*)  alloc((size_t)N_NODES * 4);
    float* invcnt  = (float*)alloc((size_t)N_NODES * N_REL * 4);           // 2.8 MB
    float* pooled  = (float*)alloc((size_t)NPOOL * N_GRAPHS * HID * 4);    // 16 KB
    (void)ws_size; (void)in_sizes; (void)n_in; (void)out_size;

    const int* src = edge_ix;
    const int* dst = edge_ix + N_EDGES;

    // setup: Wbf build + bcur init + pooled zero (one launch)
    build_wbf<<<(KPAD * NC + 255) / 256, 256, 0, stream>>>(W_root, W_rel, Wbf,
                                                           bcur, pooled);

    // gemm overlapped with edge binning (independent work, one launch)
    gemm_bin<<<GRID_MERGED, 256, 0, stream>>>(node_x, (const uint4*)Wbf, Hr, Hm,
                                              src, dst, e_attr, bcur, rec);

    bucket_sort<<<N_BUCKETS, 256, 0, stream>>>(rec, bcur, deg, offsb, invcnt);

    gather_agg<<<(N_NODES + 7) / 8, 256, 0, stream>>>(rec, offsb, deg, invcnt,
                                                      bias, Hm, Hr, batch, pooled);

    fc_kernel<<<1, 64, 0, stream>>>(pooled, fc_w, fc_b, out);
}

// Round 9
// 438.592 us; speedup vs baseline: 1.1654x; 1.1654x over previous
//
#include <hip/hip_runtime.h>

#define N_NODES 100000
#define N_EDGES 1600000
#define IN_DIM 500
#define HID 32
#define N_REL 7
#define OUT_DIM 4
#define N_GRAPHS 16
#define NC 256      // (N_REL + 1) * HID: [root | rel0..rel6]
#define MC 224      // message cols (N_REL * HID)
#define KPAD 512

// dst-bucketing: 64 nodes/bucket; 8 sub-cursors/bucket keyed by TRUE XCD id
// (s_getreg HW_REG_XCC_ID, learn_hip m09) -> rec sub-regions are XCD-exclusive
// -> full-line L2 fills, no cross-XCD partial-dirty write amplification.
#define BK_SHIFT 6
#define BK_NODES 64
#define N_BUCKETS ((N_NODES + BK_NODES - 1) / BK_NODES)   // 1563
#define NSUB 8
#define SUB_CAP 320              // mean 128/slot, sigma ~12 + XCD skew margin
#define BK_CAP (NSUB * SUB_CAP)  // 2560
#define NPOOL 8

// merged gemm+bin grid: groups of 8 consecutive blocks; every 5th group gemm
// (1563 gemm : 6250 bin ~ 1:4), both roles stripe across XCDs.
#define GEMM_BLOCKS ((N_NODES + 63) / 64)        // 1563
#define BIN_BLOCKS  ((N_EDGES + 255) / 256)      // 6250
#define N_GROUPS 978                             // 196 gemm + 782 bin groups
#define GRID_MERGED (N_GROUPS * 8)               // 7824

typedef __attribute__((ext_vector_type(8))) short bf16x8;
typedef __attribute__((ext_vector_type(4))) float f32x4;

__device__ inline unsigned short f2bf(float f) {
    unsigned u = __float_as_uint(f);
    unsigned r = (u + 0x7FFFu + ((u >> 16) & 1u)) >> 16;
    return (unsigned short)r;
}
__device__ inline float bf2f(unsigned short b) {
    return __uint_as_float((unsigned)b << 16);
}
__device__ inline unsigned xcc_id() {
    unsigned x;
    asm volatile("s_getreg_b32 %0, hwreg(HW_REG_XCC_ID)" : "=s"(x));
    return x & 7u;
}

// ---------------- build Wbf + init bcur + zero pooled (fused tiny setup) ---
__global__ void build_wbf(const float* __restrict__ W_root,
                          const float* __restrict__ W_rel,
                          unsigned short* __restrict__ Wbf,
                          int* __restrict__ bcur,
                          float* __restrict__ pooled) {
    int idx = blockIdx.x * blockDim.x + threadIdx.x;   // 0 .. KPAD*NC-1
    if (idx < N_BUCKETS * NSUB) bcur[idx] = idx * SUB_CAP;
    if (idx < NPOOL * N_GRAPHS * HID) pooled[idx] = 0.f;
    if (idx >= KPAD * NC) return;
    int kk = idx >> 8;
    int n = idx & 255;
    float v = 0.f;
    if (kk < IN_DIM) {
        if (n < HID) v = W_root[kk * HID + n];
        else {
            int r = (n >> 5) - 1;
            v = W_rel[((size_t)r * IN_DIM + kk) * HID + (n & 31)];
        }
    }
    int ks = kk >> 5, q = (kk >> 3) & 3, j = kk & 7;
    Wbf[(size_t)((((ks << 2) + q) << 8) + n) * 8 + j] = f2bf(v);
}

// ---------------- merged: MFMA GEMM (M=64, LDS, Wbf-prefetch) + bin_edges --
// gemm: [Hr fp32 | Hm bf16] = bf16(A) @ Wbf, 64x256 tile, 4 waves, 32KB LDS.
// Per ksl the next ksl's Wbf fragments are prefetched (reg rotation, +16
// VGPR) so the ~200cyc L2 latency overlaps the 16 MFMAs. launch_bounds
// (256,3) gives the allocator ~170 VGPR so the rotation cannot spill.
// bin: scatter edges into (bucket, TRUE-XCD) sub-regions of rec.
__global__ __launch_bounds__(256, 3) void gemm_bin(const float* __restrict__ A,
                                                   const uint4* __restrict__ Wbf,
                                                   float* __restrict__ Hr,
                                                   unsigned short* __restrict__ Hm,
                                                   const int* __restrict__ src,
                                                   const int* __restrict__ dst,
                                                   const int* __restrict__ attr,
                                                   int* __restrict__ bcur,
                                                   int* __restrict__ rec) {
    const int grp = blockIdx.x >> 3, j8 = blockIdx.x & 7;

    if (grp % 5 != 0) {
        // ---------------- bin_edges role ----------------
        int bb = (grp - grp / 5 - 1) * 8 + j8;
        if (bb >= BIN_BLOCKS) return;
        int e = bb * 256 + threadIdx.x;
        if (e >= N_EDGES) return;
        unsigned xcc = xcc_id();                 // true XCD of this block
        int d = dst[e];
        int cur = (d >> BK_SHIFT) * NSUB + (int)xcc;
        int p = atomicAdd(&bcur[cur], 1);
        if (p < (cur + 1) * SUB_CAP)   // overflow guard (prob ~ 0)
            rec[p] = ((d & (BK_NODES - 1)) << 20) | (src[e] << 3) | attr[e];
        return;
    }

    // ---------------- gemm role ----------------
    int bid = (grp / 5) * 8 + j8;
    if (bid >= GEMM_BLOCKS) return;

    __shared__ uint4 Alds[32 * 64];   // 32 KB: entry(ksq_local, row^swz)

    const int tid = threadIdx.x;
    const int wave = tid >> 6, lane = tid & 63;
    const int l16 = lane & 15, q = lane >> 4;
    const int row0 = bid * 64;
    const int wn = wave * 64;

    int rows_valid = N_NODES - row0; if (rows_valid > 64) rows_valid = 64;
    const float4* Ablk4 = (const float4*)(A + (size_t)row0 * IN_DIM);

    f32x4 acc[4][4];
    #pragma unroll
    for (int mt = 0; mt < 4; mt++)
        #pragma unroll
        for (int nt = 0; nt < 4; nt++)
            #pragma unroll
            for (int r = 0; r < 4; r++) acc[mt][nt][r] = 0.f;

    for (int half = 0; half < 2; half++) {
        if (half) __syncthreads();   // prev compute done before LDS overwrite
        // ---- stage: 64 rows x 256 k ----
        #pragma unroll 4
        for (int it = 0; it < 16; it++) {
            int idx = it * 256 + tid;
            int row = idx >> 6, slot = idx & 63;
            int k = half * 256 + slot * 4;
            float4 v = make_float4(0.f, 0.f, 0.f, 0.f);
            if (row < rows_valid && k < IN_DIM)
                v = Ablk4[row * 125 + (k >> 2)];
            int ksq = slot >> 1;                       // local 0..31
            int e = (ksq << 6) | ((row ^ ksq) & 63);
            ushort4 b;
            b.x = f2bf(v.x); b.y = f2bf(v.y); b.z = f2bf(v.z); b.w = f2bf(v.w);
            *(ushort4*)((unsigned short*)&Alds[e] + (slot & 1) * 4) = b;
        }
        __syncthreads();
        // ---- compute 8 k-steps, Wbf prefetched one ksl ahead ----
        bf16x8 bnxt[4];
        {
            int kg0 = (half * 32 + q) << 8;            // ksl = 0
            #pragma unroll
            for (int nt = 0; nt < 4; nt++) {
                uint4 t = Wbf[(size_t)kg0 + wn + nt * 16 + l16];
                bnxt[nt] = *(bf16x8*)&t;
            }
        }
        #pragma unroll
        for (int ksl = 0; ksl < 8; ksl++) {
            bf16x8 bcur4[4];
            #pragma unroll
            for (int nt = 0; nt < 4; nt++) bcur4[nt] = bnxt[nt];
            if (ksl < 7) {
                int kg = (half * 32 + (ksl + 1) * 4 + q) << 8;
                #pragma unroll
                for (int nt = 0; nt < 4; nt++) {
                    uint4 t = Wbf[(size_t)kg + wn + nt * 16 + l16];
                    bnxt[nt] = *(bf16x8*)&t;
                }
            }
            int ksq_l = ksl * 4 + q;
            bf16x8 afr[4];
            #pragma unroll
            for (int mt = 0; mt < 4; mt++)
                afr[mt] = *(const bf16x8*)&Alds[(ksq_l << 6) | (((mt * 16 + l16) ^ ksq_l) & 63)];
            #pragma unroll
            for (int mt = 0; mt < 4; mt++)
                #pragma unroll
                for (int nt = 0; nt < 4; nt++)
                    acc[mt][nt] = __builtin_amdgcn_mfma_f32_16x16x32_bf16(
                        afr[mt], bcur4[nt], acc[mt][nt], 0, 0, 0);
        }
    }

    // ---- store: C/D layout col=lane&15, row=(lane>>4)*4+reg ----
    #pragma unroll
    for (int mt = 0; mt < 4; mt++) {
        int rbase = row0 + mt * 16 + q * 4;
        #pragma unroll
        for (int r = 0; r < 4; r++) {
            int row = rbase + r;
            if (row < N_NODES) {
                #pragma unroll
                for (int nt = 0; nt < 4; nt++) {
                    int col = wn + nt * 16 + l16;
                    float v = acc[mt][nt][r];
                    if (wave == 0 && nt < 2)            // col < 32: root slice
                        Hr[(size_t)row * HID + col] = v;
                    else
                        Hm[(size_t)row * MC + (col - HID)] = f2bf(v);
                }
            }
        }
    }
}

// ---------------- per-bucket LDS counting sort + deg/offs/invcnt -----------
__global__ __launch_bounds__(256) void bucket_sort(int* __restrict__ rec,
                                                   const int* __restrict__ bcur,
                                                   int* __restrict__ deg,
                                                   int* __restrict__ offs,
                                                   float* __restrict__ invcnt) {
    __shared__ int h2[BK_NODES * N_REL];   // per-(node,rel) counts
    __shared__ int lcur[BK_NODES];         // scatter cursors
    __shared__ int sorted[BK_CAP];         // 10 KB
    __shared__ int scnt[NSUB];
    __shared__ int s_total;

    const int b = blockIdx.x, t = threadIdx.x;
    const int n0 = b << BK_SHIFT;
    const size_t rbase = (size_t)b * BK_CAP;

    for (int i = t; i < BK_NODES * N_REL; i += 256) h2[i] = 0;
    if (t < NSUB) {
        int c = bcur[b * NSUB + t] - (b * NSUB + t) * SUB_CAP;
        scnt[t] = c < SUB_CAP ? c : SUB_CAP;
    }
    __syncthreads();

    for (int s = 0; s < NSUB; s++) {
        int cs = scnt[s];
        const int* rp = rec + rbase + s * SUB_CAP;
        for (int i = t; i < cs; i += 256) {
            int q = rp[i];
            atomicAdd(&h2[(q >> 20) * N_REL + (q & 7)], 1);
        }
    }
    __syncthreads();

    if (t < BK_NODES) {       // wave 0: per-node totals + exclusive scan
        int tot = 0;
        #pragma unroll
        for (int r = 0; r < N_REL; r++) tot += h2[t * N_REL + r];
        int incl = tot;
        #pragma unroll
        for (int off = 1; off < BK_NODES; off <<= 1) {
            int y = __shfl_up(incl, off, 64);
            if (t >= off) incl += y;
        }
        int excl = incl - tot;
        lcur[t] = excl;
        if (t == BK_NODES - 1) s_total = incl;
        int n = n0 + t;
        if (n < N_NODES) {
            deg[n] = tot;
            offs[n] = (int)rbase + excl;
        }
    }
    int lim = (N_NODES - n0) * N_REL;
    if (lim > BK_NODES * N_REL) lim = BK_NODES * N_REL;
    for (int i = t; i < lim; i += 256) {
        int cc = h2[i];
        invcnt[(size_t)n0 * N_REL + i] = 1.0f / (float)(cc > 1 ? cc : 1);
    }
    __syncthreads();

    for (int s = 0; s < NSUB; s++) {
        int cs = scnt[s];
        const int* rp = rec + rbase + s * SUB_CAP;
        for (int i = t; i < cs; i += 256) {
            int q = rp[i];
            int p = atomicAdd(&lcur[q >> 20], 1);
            if (p < BK_CAP)                       // defensive
                sorted[p] = q & 0xFFFFF;          // strip ldst: (src<<3)|rel
        }
    }
    __syncthreads();

    int total = s_total;
    if (total > BK_CAP) total = BK_CAP;           // defensive
    for (int i = t; i < total; i += 256) rec[rbase + i] = sorted[i];
}

// ---------------- gather aggregation: one HALF-wave (32 lanes) per node ----
// fully predicated 8-deep loop; fused relu+bias+graph pooling.
__global__ __launch_bounds__(256) void gather_agg(const int* __restrict__ rec,
                                                  const int* __restrict__ offs,
                                                  const int* __restrict__ deg,
                                                  const float* __restrict__ invcnt,
                                                  const float* __restrict__ bias,
                                                  const unsigned short* __restrict__ Hm,
                                                  const float* __restrict__ Hr,
                                                  const int* __restrict__ batch,
                                                  float* __restrict__ pooled) {
    __shared__ float lpool[N_GRAPHS][HID];
    const int t = threadIdx.x;
    for (int i = t; i < N_GRAPHS * HID; i += 256) ((float*)lpool)[i] = 0.f;
    __syncthreads();

    const int d = blockIdx.x * 8 + (t >> 5);   // 12500*8 == N_NODES exactly
    const int c = t & 31;

    int dg = deg[d];
    int start = offs[d];
    int end = start + dg;

    float acc = 0.f;
    // predicated 8-deep: rec reads beyond end stay inside ws (bucket slack);
    // masked records forced to q=0, weight=0.
    for (int i = start; i < end; i += 8) {
        int q[8];
        float h[8], w[8];
        #pragma unroll
        for (int j = 0; j < 8; j++) {
            bool ok = (i + j) < end;
            int qq = rec[i + j];
            q[j] = ok ? qq : 0;
            w[j] = ok ? 1.f : 0.f;
        }
        #pragma unroll
        for (int j = 0; j < 8; j++)
            h[j] = bf2f(Hm[(size_t)((q[j] >> 3) & 0x1FFFF) * MC + (q[j] & 7) * HID + c]);
        #pragma unroll
        for (int j = 0; j < 8; j++)
            acc = fmaf(h[j], w[j] * invcnt[d * N_REL + (q[j] & 7)], acc);
    }

    float v = Hr[(size_t)d * HID + c] + bias[c] + acc;
    v = fmaxf(v, 0.f);
    atomicAdd(&lpool[batch[d]][c], v);
    __syncthreads();

    // flush to the partial slice of this block's TRUE XCD -> atomic chains
    // stay XCD-local.
    float* pp = pooled + (size_t)xcc_id() * N_GRAPHS * HID;
    for (int i2 = t; i2 < N_GRAPHS * HID; i2 += 256) {
        float v2 = ((float*)lpool)[i2];
        if (v2 != 0.f) atomicAdd(&pp[i2], v2);
    }
}

// ---------------- final FC (sums the NPOOL partial slices) ----------
__global__ void fc_kernel(const float* __restrict__ pooled, const float* __restrict__ fc_w,
                          const float* __restrict__ fc_b, float* __restrict__ out) {
    int t = threadIdx.x;
    if (t >= N_GRAPHS * OUT_DIM) return;
    int g = t >> 2, o = t & 3;
    float acc = fc_b[o];
    #pragma unroll
    for (int c = 0; c < HID; c++) {
        float p = 0.f;
        #pragma unroll
        for (int k = 0; k < NPOOL; k++)
            p += pooled[(size_t)(k * N_GRAPHS + g) * HID + c];
        acc += p * fc_w[c * OUT_DIM + o];
    }
    out[t] = acc;
}

extern "C" void kernel_launch(void* const* d_in, const int* in_sizes, int n_in,
                              void* d_out, int out_size, void* d_ws, size_t ws_size,
                              hipStream_t stream) {
    const float* node_x  = (const float*)d_in[0];
    const int*   edge_ix = (const int*)d_in[1];
    const int*   e_attr  = (const int*)d_in[2];
    const int*   batch   = (const int*)d_in[3];
    const float* W_rel   = (const float*)d_in[4];
    const float* W_root  = (const float*)d_in[5];
    const float* bias    = (const float*)d_in[6];
    const float* fc_w    = (const float*)d_in[7];
    const float* fc_b    = (const float*)d_in[8];
    float* out = (float*)d_out;

    char* ws = (char*)d_ws;
    size_t off = 0;
    auto alloc = [&](size_t bytes) {
        char* p = ws + off;
        off += (bytes + 255) & ~(size_t)255;
        return p;
    };
    unsigned short* Wbf = (unsigned short*)alloc((size_t)KPAD * NC * 2);   // 256 KB
    float* Hr      = (float*)alloc((size_t)N_NODES * HID * 4);             // 12.8 MB
    unsigned short* Hm = (unsigned short*)alloc((size_t)N_NODES * MC * 2); // 44.8 MB
    int*   rec     = (int*)  alloc((size_t)N_BUCKETS * BK_CAP * 4);        // 16.0 MB
    int*   bcur    = (int*)  alloc((size_t)N_BUCKETS * NSUB * 4);          // 50 KB
    int*   deg     = (int*)  alloc((size_t)N_NODES * 4);
    int*   offsb   = (int*)  alloc((size_t)N_NODES * 4);
    float* invcnt  = (float*)alloc((size_t)N_NODES * N_REL * 4);           // 2.8 MB
    float* pooled  = (float*)alloc((size_t)NPOOL * N_GRAPHS * HID * 4);    // 16 KB
    (void)ws_size; (void)in_sizes; (void)n_in; (void)out_size;

    const int* src = edge_ix;
    const int* dst = edge_ix + N_EDGES;

    // setup: Wbf build + bcur init + pooled zero (one launch)
    build_wbf<<<(KPAD * NC + 255) / 256, 256, 0, stream>>>(W_root, W_rel, Wbf,
                                                           bcur, pooled);

    // gemm overlapped with edge binning (independent work, one launch)
    gemm_bin<<<GRID_MERGED, 256, 0, stream>>>(node_x, (const uint4*)Wbf, Hr, Hm,
                                              src, dst, e_attr, bcur, rec);

    bucket_sort<<<N_BUCKETS, 256, 0, stream>>>(rec, bcur, deg, offsb, invcnt);

    gather_agg<<<(N_NODES + 7) / 8, 256, 0, stream>>>(rec, offsb, deg, invcnt,
                                                      bias, Hm, Hr, batch, pooled);

    fc_kernel<<<1, 64, 0, stream>>>(pooled, fc_w, fc_b, out);
}

// Round 10
// 408.754 us; speedup vs baseline: 1.2505x; 1.0730x over previous
//
#include <hip/hip_runtime.h>

#define N_NODES 100000
#define N_EDGES 1600000
#define IN_DIM 500
#define HID 32
#define N_REL 7
#define OUT_DIM 4
#define N_GRAPHS 16
#define NC 256      // (N_REL + 1) * HID: [root | rel0..rel6]
#define MC 224      // message cols (N_REL * HID)
#define KPAD 512

// dst-bucketing: 64 nodes/bucket; 8 sub-cursors/bucket (indexed blockIdx&7)
#define BK_SHIFT 6
#define BK_NODES 64
#define N_BUCKETS ((N_NODES + BK_NODES - 1) / BK_NODES)   // 1563
#define NSUB 8
#define SUB_CAP 256
#define BK_CAP (NSUB * SUB_CAP)  // 2048
#define NPOOL 8

// merged gemm+bin grid: groups of 8 consecutive blocks; every 3rd group gemm
// (3125 gemm : 6250 bin = 1:2), both roles stripe across XCDs.
#define GEMM_BLOCKS 3125                         // 3125*32 == N_NODES exactly
#define BIN_BLOCKS  ((N_EDGES + 255) / 256)      // 6250
#define N_GROUPS 1173                            // 391 gemm + 782 bin groups
#define GRID_MERGED (N_GROUPS * 8)               // 9384

typedef __attribute__((ext_vector_type(8))) short bf16x8;
typedef __attribute__((ext_vector_type(4))) float f32x4;

__device__ inline unsigned short f2bf(float f) {
    unsigned u = __float_as_uint(f);
    unsigned r = (u + 0x7FFFu + ((u >> 16) & 1u)) >> 16;
    return (unsigned short)r;
}
__device__ inline float bf2f(unsigned short b) {
    return __uint_as_float((unsigned)b << 16);
}

// ---------------- build Wbf + init bcur + zero pooled (fused tiny setup) ---
__global__ void build_wbf(const float* __restrict__ W_root,
                          const float* __restrict__ W_rel,
                          unsigned short* __restrict__ Wbf,
                          int* __restrict__ bcur,
                          float* __restrict__ pooled) {
    int idx = blockIdx.x * blockDim.x + threadIdx.x;   // 0 .. KPAD*NC-1
    if (idx < N_BUCKETS * NSUB) bcur[idx] = idx * SUB_CAP;
    if (idx < NPOOL * N_GRAPHS * HID) pooled[idx] = 0.f;
    if (idx >= KPAD * NC) return;
    int kk = idx >> 8;
    int n = idx & 255;
    float v = 0.f;
    if (kk < IN_DIM) {
        if (n < HID) v = W_root[kk * HID + n];
        else {
            int r = (n >> 5) - 1;
            v = W_rel[((size_t)r * IN_DIM + kk) * HID + (n & 31)];
        }
    }
    int ks = kk >> 5, q = (kk >> 3) & 3, j = kk & 7;
    Wbf[(size_t)((((ks << 2) + q) << 8) + n) * 8 + j] = f2bf(v);
}

// ---------------- merged: MFMA GEMM (M=32, async gload_lds) + bin_edges ----
// gemm: [Hr fp32 | Hm bf16] = bf16(A) @ Wbf, 32x256 tile, 4 waves, 32KB LDS.
// Stage = 8x global_load_lds dwordx4 per thread (no VGPR round-trip, no
// VALU): LDS holds fp32, linear per row; global SOURCE granule pre-swizzled
// g ^= (row&7), compute reads granule (2K)^s -> conflict-distributed (both-
// sides swizzle, rule #21). bf16 conversion in compute via v_cvt_pk_bf16_f32.
// K-tail: source granule clamped to 60 (half 1); garbage k>=500 annihilated
// by Wbf zero rows. bin: scatter edges into (bucket, j8) sub-regions.
__global__ __launch_bounds__(256, 4) void gemm_bin(const float* __restrict__ A,
                                                   const uint4* __restrict__ Wbf,
                                                   float* __restrict__ Hr,
                                                   unsigned short* __restrict__ Hm,
                                                   const int* __restrict__ src,
                                                   const int* __restrict__ dst,
                                                   const int* __restrict__ attr,
                                                   int* __restrict__ bcur,
                                                   int* __restrict__ rec) {
    const int grp = blockIdx.x >> 3, j8 = blockIdx.x & 7;

    if (grp % 3 != 0) {
        // ---------------- bin_edges role ----------------
        int bb = (grp - grp / 3 - 1) * 8 + j8;
        if (bb >= BIN_BLOCKS) return;
        int e = bb * 256 + threadIdx.x;
        if (e >= N_EDGES) return;
        int d = dst[e];
        int cur = (d >> BK_SHIFT) * NSUB + j8;
        int p = atomicAdd(&bcur[cur], 1);
        if (p < (cur + 1) * SUB_CAP)   // overflow guard (prob ~ 0)
            rec[p] = ((d & (BK_NODES - 1)) << 20) | (src[e] << 3) | attr[e];
        return;
    }

    // ---------------- gemm role ----------------
    int bid = (grp / 3) * 8 + j8;
    if (bid >= GEMM_BLOCKS) return;

    __shared__ float4 AldsG[32 * 64];   // 32 KB fp32: [row][granule], src-swizzled

    const int tid = threadIdx.x;
    const int wave = tid >> 6, lane = tid & 63;
    const int l16 = lane & 15, q = lane >> 4;
    const int row0 = bid * 32;
    const int wn = wave * 64;

    f32x4 acc[2][4];
    #pragma unroll
    for (int mt = 0; mt < 2; mt++)
        #pragma unroll
        for (int nt = 0; nt < 4; nt++)
            #pragma unroll
            for (int r = 0; r < 4; r++) acc[mt][nt][r] = 0.f;

    for (int half = 0; half < 2; half++) {
        if (half) __syncthreads();   // all compute reads of prev half done
        // ---- async stage: one row per wave-iter; LDS granule lane <- A granule lane^s
        #pragma unroll
        for (int it = 0; it < 8; it++) {
            int row = wave * 8 + it;                 // uniform per wave
            int s = row & 7;
            int sg = lane ^ s;                       // source granule 0..63
            if (half) sg = sg < 60 ? sg : 60;        // tail clamp (k>=500)
            const float* gp = A + (size_t)(row0 + row) * IN_DIM + half * 256 + sg * 4;
            __builtin_amdgcn_global_load_lds(
                (const __attribute__((address_space(1))) void*)gp,
                (__attribute__((address_space(3))) void*)&AldsG[row * 64],
                16, 0, 0);
        }
        __syncthreads();             // compiler drains vmcnt before barrier
        // ---- compute 8 k-steps ----
        #pragma unroll 2
        for (int ksl = 0; ksl < 8; ksl++) {
            int K = ksl * 4 + q;                     // 8-float quantum 0..31
            int ksq_g = half * 32 + K;
            bf16x8 bfr[4];
            #pragma unroll
            for (int nt = 0; nt < 4; nt++) {
                uint4 t = Wbf[(size_t)(ksq_g << 8) + wn + nt * 16 + l16];
                bfr[nt] = *(bf16x8*)&t;
            }
            #pragma unroll
            for (int mt = 0; mt < 2; mt++) {
                int row = mt * 16 + l16;
                int s = row & 7;
                int g0 = (2 * K) ^ s;
                float4 fa = *(const float4*)&AldsG[row * 64 + g0];        // k..k+3
                float4 fb = *(const float4*)&AldsG[row * 64 + (g0 ^ 1)];  // k+4..k+7
                union { unsigned u[4]; bf16x8 v; } af;
                asm("v_cvt_pk_bf16_f32 %0, %1, %2" : "=v"(af.u[0]) : "v"(fa.x), "v"(fa.y));
                asm("v_cvt_pk_bf16_f32 %0, %1, %2" : "=v"(af.u[1]) : "v"(fa.z), "v"(fa.w));
                asm("v_cvt_pk_bf16_f32 %0, %1, %2" : "=v"(af.u[2]) : "v"(fb.x), "v"(fb.y));
                asm("v_cvt_pk_bf16_f32 %0, %1, %2" : "=v"(af.u[3]) : "v"(fb.z), "v"(fb.w));
                #pragma unroll
                for (int nt = 0; nt < 4; nt++)
                    acc[mt][nt] = __builtin_amdgcn_mfma_f32_16x16x32_bf16(
                        af.v, bfr[nt], acc[mt][nt], 0, 0, 0);
            }
        }
    }

    // ---- store: C/D layout col=lane&15, row=(lane>>4)*4+reg ----
    #pragma unroll
    for (int mt = 0; mt < 2; mt++) {
        int rbase = row0 + mt * 16 + q * 4;
        #pragma unroll
        for (int r = 0; r < 4; r++) {
            int row = rbase + r;
            #pragma unroll
            for (int nt = 0; nt < 4; nt++) {
                int col = wn + nt * 16 + l16;
                float v = acc[mt][nt][r];
                if (wave == 0 && nt < 2)            // col < 32: root slice
                    Hr[(size_t)row * HID + col] = v;
                else
                    Hm[(size_t)row * MC + (col - HID)] = f2bf(v);
            }
        }
    }
}

// ---------------- per-bucket LDS counting sort + deg/offs/invcnt -----------
__global__ __launch_bounds__(256) void bucket_sort(int* __restrict__ rec,
                                                   const int* __restrict__ bcur,
                                                   int* __restrict__ deg,
                                                   int* __restrict__ offs,
                                                   float* __restrict__ invcnt) {
    __shared__ int h2[BK_NODES * N_REL];   // per-(node,rel) counts
    __shared__ int lcur[BK_NODES];         // scatter cursors
    __shared__ int sorted[BK_CAP];         // 8 KB
    __shared__ int scnt[NSUB];
    __shared__ int s_total;

    const int b = blockIdx.x, t = threadIdx.x;
    const int n0 = b << BK_SHIFT;
    const size_t rbase = (size_t)b * BK_CAP;

    for (int i = t; i < BK_NODES * N_REL; i += 256) h2[i] = 0;
    if (t < NSUB) {
        int c = bcur[b * NSUB + t] - (b * NSUB + t) * SUB_CAP;
        scnt[t] = c < SUB_CAP ? c : SUB_CAP;
    }
    __syncthreads();

    for (int s = 0; s < NSUB; s++) {
        int cs = scnt[s];
        const int* rp = rec + rbase + s * SUB_CAP;
        for (int i = t; i < cs; i += 256) {
            int q = rp[i];
            atomicAdd(&h2[(q >> 20) * N_REL + (q & 7)], 1);
        }
    }
    __syncthreads();

    if (t < BK_NODES) {       // wave 0: per-node totals + exclusive scan
        int tot = 0;
        #pragma unroll
        for (int r = 0; r < N_REL; r++) tot += h2[t * N_REL + r];
        int incl = tot;
        #pragma unroll
        for (int off = 1; off < BK_NODES; off <<= 1) {
            int y = __shfl_up(incl, off, 64);
            if (t >= off) incl += y;
        }
        int excl = incl - tot;
        lcur[t] = excl;
        if (t == BK_NODES - 1) s_total = incl;
        int n = n0 + t;
        if (n < N_NODES) {
            deg[n] = tot;
            offs[n] = (int)rbase + excl;
        }
    }
    int lim = (N_NODES - n0) * N_REL;
    if (lim > BK_NODES * N_REL) lim = BK_NODES * N_REL;
    for (int i = t; i < lim; i += 256) {
        int cc = h2[i];
        invcnt[(size_t)n0 * N_REL + i] = 1.0f / (float)(cc > 1 ? cc : 1);
    }
    __syncthreads();

    for (int s = 0; s < NSUB; s++) {
        int cs = scnt[s];
        const int* rp = rec + rbase + s * SUB_CAP;
        for (int i = t; i < cs; i += 256) {
            int q = rp[i];
            int p = atomicAdd(&lcur[q >> 20], 1);
            if (p < BK_CAP)                       // defensive
                sorted[p] = q & 0xFFFFF;          // strip ldst: (src<<3)|rel
        }
    }
    __syncthreads();

    int total = s_total;
    if (total > BK_CAP) total = BK_CAP;           // defensive
    for (int i = t; i < total; i += 256) rec[rbase + i] = sorted[i];
}

// ---------------- gather aggregation: one HALF-wave (32 lanes) per node ----
// fully predicated 8-deep loop; fused relu+bias+graph pooling.
__global__ __launch_bounds__(256) void gather_agg(const int* __restrict__ rec,
                                                  const int* __restrict__ offs,
                                                  const int* __restrict__ deg,
                                                  const float* __restrict__ invcnt,
                                                  const float* __restrict__ bias,
                                                  const unsigned short* __restrict__ Hm,
                                                  const float* __restrict__ Hr,
                                                  const int* __restrict__ batch,
                                                  float* __restrict__ pooled) {
    __shared__ float lpool[N_GRAPHS][HID];
    const int t = threadIdx.x;
    for (int i = t; i < N_GRAPHS * HID; i += 256) ((float*)lpool)[i] = 0.f;
    __syncthreads();

    const int d = blockIdx.x * 8 + (t >> 5);   // 12500*8 == N_NODES exactly
    const int c = t & 31;

    int dg = deg[d];
    int start = offs[d];
    int end = start + dg;

    float acc = 0.f;
    // predicated 8-deep: rec reads beyond end stay inside ws (bucket slack);
    // masked records forced to q=0, weight=0.
    for (int i = start; i < end; i += 8) {
        int q[8];
        float h[8], w[8];
        #pragma unroll
        for (int j = 0; j < 8; j++) {
            bool ok = (i + j) < end;
            int qq = rec[i + j];
            q[j] = ok ? qq : 0;
            w[j] = ok ? 1.f : 0.f;
        }
        #pragma unroll
        for (int j = 0; j < 8; j++)
            h[j] = bf2f(Hm[(size_t)((q[j] >> 3) & 0x1FFFF) * MC + (q[j] & 7) * HID + c]);
        #pragma unroll
        for (int j = 0; j < 8; j++)
            acc = fmaf(h[j], w[j] * invcnt[d * N_REL + (q[j] & 7)], acc);
    }

    float v = Hr[(size_t)d * HID + c] + bias[c] + acc;
    v = fmaxf(v, 0.f);
    atomicAdd(&lpool[batch[d]][c], v);
    __syncthreads();

    float* pp = pooled + (size_t)(blockIdx.x & (NPOOL - 1)) * N_GRAPHS * HID;
    for (int i2 = t; i2 < N_GRAPHS * HID; i2 += 256) {
        float v2 = ((float*)lpool)[i2];
        if (v2 != 0.f) atomicAdd(&pp[i2], v2);
    }
}

// ---------------- final FC (sums the NPOOL partial slices) ----------
__global__ void fc_kernel(const float* __restrict__ pooled, const float* __restrict__ fc_w,
                          const float* __restrict__ fc_b, float* __restrict__ out) {
    int t = threadIdx.x;
    if (t >= N_GRAPHS * OUT_DIM) return;
    int g = t >> 2, o = t & 3;
    float acc = fc_b[o];
    #pragma unroll
    for (int c = 0; c < HID; c++) {
        float p = 0.f;
        #pragma unroll
        for (int k = 0; k < NPOOL; k++)
            p += pooled[(size_t)(k * N_GRAPHS + g) * HID + c];
        acc += p * fc_w[c * OUT_DIM + o];
    }
    out[t] = acc;
}

extern "C" void kernel_launch(void* const* d_in, const int* in_sizes, int n_in,
                              void* d_out, int out_size, void* d_ws, size_t ws_size,
                              hipStream_t stream) {
    const float* node_x  = (const float*)d_in[0];
    const int*   edge_ix = (const int*)d_in[1];
    const int*   e_attr  = (const int*)d_in[2];
    const int*   batch   = (const int*)d_in[3];
    const float* W_rel   = (const float*)d_in[4];
    const float* W_root  = (const float*)d_in[5];
    const float* bias    = (const float*)d_in[6];
    const float* fc_w    = (const float*)d_in[7];
    const float* fc_b    = (const float*)d_in[8];
    float* out = (float*)d_out;

    char* ws = (char*)d_ws;
    size_t off = 0;
    auto alloc = [&](size_t bytes) {
        char* p = ws + off;
        off += (bytes + 255) & ~(size_t)255;
        return p;
    };
    unsigned short* Wbf = (unsigned short*)alloc((size_t)KPAD * NC * 2);   // 256 KB
    float* Hr      = (float*)alloc((size_t)N_NODES * HID * 4);             // 12.8 MB
    unsigned short* Hm = (unsigned short*)alloc((size_t)N_NODES * MC * 2); // 44.8 MB
    int*   rec     = (int*)  alloc((size_t)N_BUCKETS * BK_CAP * 4);        // 12.8 MB
    int*   bcur    = (int*)  alloc((size_t)N_BUCKETS * NSUB * 4);          // 50 KB
    int*   deg     = (int*)  alloc((size_t)N_NODES * 4);
    int*   offsb   = (int*)  alloc((size_t)N_NODES * 4);
    float* invcnt  = (float*)alloc((size_t)N_NODES * N_REL * 4);           // 2.8 MB
    float* pooled  = (float*)alloc((size_t)NPOOL * N_GRAPHS * HID * 4);    // 16 KB
    (void)ws_size; (void)in_sizes; (void)n_in; (void)out_size;

    const int* src = edge_ix;
    const int* dst = edge_ix + N_EDGES;

    // setup: Wbf build + bcur init + pooled zero (one launch)
    build_wbf<<<(KPAD * NC + 255) / 256, 256, 0, stream>>>(W_root, W_rel, Wbf,
                                                           bcur, pooled);

    // gemm overlapped with edge binning (independent work, one launch)
    gemm_bin<<<GRID_MERGED, 256, 0, stream>>>(node_x, (const uint4*)Wbf, Hr, Hm,
                                              src, dst, e_attr, bcur, rec);

    bucket_sort<<<N_BUCKETS, 256, 0, stream>>>(rec, bcur, deg, offsb, invcnt);

    gather_agg<<<(N_NODES + 7) / 8, 256, 0, stream>>>(rec, offsb, deg, invcnt,
                                                      bias, Hm, Hr, batch, pooled);

    fc_kernel<<<1, 64, 0, stream>>>(pooled, fc_w, fc_b, out);
}